// Round 1
// baseline (265.803 us; speedup 1.0000x reference)
//
#include <hip/hip_runtime.h>
#include <math.h>

#define NATOMS 4096
#define R_CUT 5.0f
#define JPT 4                 // j's per thread
#define BLOCK 256
#define JPB (BLOCK * JPT)     // 1024 j's per block

__global__ __launch_bounds__(BLOCK) void radius_graph_kernel(
    const float* __restrict__ pos,    // [N,3]
    const float* __restrict__ cell,   // [B,3,3]
    const int*   __restrict__ batch,  // [N]
    float* __restrict__ disp_out,     // [N,N,3]
    float* __restrict__ mask_out)     // [N,N] as 0/1 float
{
    __shared__ float sA[9];   // inv(cell^T) for this row's graph
    __shared__ float sC[9];   // cell for this row's graph
    __shared__ float sPi[3];  // pos[i]
    __shared__ int   sBi;     // batch[i]

    const int bid = blockIdx.x;
    const int i   = bid >> 2;        // 4 blocks per row (4096 / 1024)
    const int jc  = bid & 3;

    if (threadIdx.x == 0) {
        const int b = batch[i];
        sBi = b;
        const float* C = cell + b * 9;
        const float C00 = C[0], C01 = C[1], C02 = C[2];
        const float C10 = C[3], C11 = C[4], C12 = C[5];
        const float C20 = C[6], C21 = C[7], C22 = C[8];
        // A = inv(C^T) = cofactor(C) / det(C)
        const float cof00 =  (C11 * C22 - C12 * C21);
        const float cof01 = -(C10 * C22 - C12 * C20);
        const float cof02 =  (C10 * C21 - C11 * C20);
        const float cof10 = -(C01 * C22 - C02 * C21);
        const float cof11 =  (C00 * C22 - C02 * C20);
        const float cof12 = -(C00 * C21 - C01 * C20);
        const float cof20 =  (C01 * C12 - C02 * C11);
        const float cof21 = -(C00 * C12 - C02 * C10);
        const float cof22 =  (C00 * C11 - C01 * C10);
        const float det = C00 * cof00 + C01 * cof01 + C02 * cof02;
        const float id  = 1.0f / det;
        sA[0] = cof00 * id; sA[1] = cof01 * id; sA[2] = cof02 * id;
        sA[3] = cof10 * id; sA[4] = cof11 * id; sA[5] = cof12 * id;
        sA[6] = cof20 * id; sA[7] = cof21 * id; sA[8] = cof22 * id;
        sC[0] = C00; sC[1] = C01; sC[2] = C02;
        sC[3] = C10; sC[4] = C11; sC[5] = C12;
        sC[6] = C20; sC[7] = C21; sC[8] = C22;
        sPi[0] = pos[i * 3 + 0];
        sPi[1] = pos[i * 3 + 1];
        sPi[2] = pos[i * 3 + 2];
    }
    __syncthreads();

    const int j0 = jc * JPB + (int)threadIdx.x * JPT;

    // 12 contiguous floats: pos[j0..j0+3][0..2]  (j0*3 is a multiple of 4)
    const float4* pj = (const float4*)(pos + (size_t)j0 * 3);
    const float4 q0 = pj[0], q1 = pj[1], q2 = pj[2];
    const int4 bj4 = *(const int4*)(batch + j0);

    const float pjx[4] = { q0.x, q0.w, q1.z, q2.y };
    const float pjy[4] = { q0.y, q1.x, q1.w, q2.z };
    const float pjz[4] = { q0.z, q1.y, q2.x, q2.w };
    const int   bj[4]  = { bj4.x, bj4.y, bj4.z, bj4.w };

    const float pix = sPi[0], piy = sPi[1], piz = sPi[2];
    const int   bi  = sBi;

    float od[12];
    float om[4];

    #pragma unroll
    for (int t = 0; t < 4; ++t) {
        const int j = j0 + t;
        // raw displacement, exact-order f32 (matches numpy, no fma contraction)
        const float d0 = __fsub_rn(pix, pjx[t]);
        const float d1 = __fsub_rn(piy, pjy[t]);
        const float d2 = __fsub_rn(piz, pjz[t]);

        // scaled = inv(cell^T) @ d   (ulp noise here is harmless: it only
        // matters near scaled==±0.5, i.e. half-cell disp >> R, masked out)
        const float s0 = __fadd_rn(__fadd_rn(__fmul_rn(sA[0], d0), __fmul_rn(sA[1], d1)), __fmul_rn(sA[2], d2));
        const float s1 = __fadd_rn(__fadd_rn(__fmul_rn(sA[3], d0), __fmul_rn(sA[4], d1)), __fmul_rn(sA[5], d2));
        const float s2 = __fadd_rn(__fadd_rn(__fmul_rn(sA[6], d0), __fmul_rn(sA[7], d1)), __fmul_rn(sA[8], d2));

        const float r0 = rintf(s0);   // round-half-even == jnp.round
        const float r1 = rintf(s1);
        const float r2 = rintf(s2);

        // wrapped = d - cell @ r, exact numpy order, no contraction
        const float w0 = __fsub_rn(d0, __fadd_rn(__fadd_rn(__fmul_rn(sC[0], r0), __fmul_rn(sC[1], r1)), __fmul_rn(sC[2], r2)));
        const float w1 = __fsub_rn(d1, __fadd_rn(__fadd_rn(__fmul_rn(sC[3], r0), __fmul_rn(sC[4], r1)), __fmul_rn(sC[5], r2)));
        const float w2 = __fsub_rn(d2, __fadd_rn(__fadd_rn(__fmul_rn(sC[6], r0), __fmul_rn(sC[7], r1)), __fmul_rn(sC[8], r2)));

        const float n2 = __fadd_rn(__fadd_rn(__fmul_rn(w0, w0), __fmul_rn(w1, w1)), __fmul_rn(w2, w2));
        const bool m = (bi == bj[t]) && (i != j) && (sqrtf(n2) < R_CUT);

        od[t * 3 + 0] = m ? w0 : 0.0f;
        od[t * 3 + 1] = m ? w1 : 0.0f;
        od[t * 3 + 2] = m ? w2 : 0.0f;
        om[t] = m ? 1.0f : 0.0f;
    }

    float4* dout = (float4*)(disp_out + (size_t)i * (NATOMS * 3) + (size_t)j0 * 3);
    dout[0] = make_float4(od[0], od[1], od[2],  od[3]);
    dout[1] = make_float4(od[4], od[5], od[6],  od[7]);
    dout[2] = make_float4(od[8], od[9], od[10], od[11]);

    float4* mout = (float4*)(mask_out + (size_t)i * NATOMS + j0);
    *mout = make_float4(om[0], om[1], om[2], om[3]);
}

extern "C" void kernel_launch(void* const* d_in, const int* in_sizes, int n_in,
                              void* d_out, int out_size, void* d_ws, size_t ws_size,
                              hipStream_t stream) {
    const float* pos   = (const float*)d_in[0];
    const float* cell  = (const float*)d_in[1];
    const int*   batch = (const int*)d_in[2];

    float* disp_out = (float*)d_out;
    float* mask_out = (float*)d_out + (size_t)NATOMS * NATOMS * 3;

    const int blocks = NATOMS * (NATOMS / JPB);  // 4096 * 4 = 16384
    radius_graph_kernel<<<blocks, BLOCK, 0, stream>>>(pos, cell, batch, disp_out, mask_out);
}

// Round 2
// 258.040 us; speedup vs baseline: 1.0301x; 1.0301x over previous
//
#include <hip/hip_runtime.h>
#include <math.h>

#define NATOMS 4096
#define R_CUT 5.0f
#define JPT 4                 // j's per thread
#define BLOCK 256
#define JPB (BLOCK * JPT)     // 1024 j's per block

__global__ __launch_bounds__(BLOCK) void radius_graph_kernel(
    const float* __restrict__ pos,    // [N,3]
    const float* __restrict__ cell,   // [B,3,3]
    const int*   __restrict__ batch,  // [N]
    float* __restrict__ disp_out,     // [N,N,3]
    float* __restrict__ mask_out)     // [N,N] as 0/1 float
{
    __shared__ float sBuf[JPB * 3];   // 12 KB staging for coalesced disp stores

    const int bid = blockIdx.x;
    const int i   = bid >> 2;        // 4 blocks per row (4096 / 1024)
    const int jc  = bid & 3;
    const int tid = (int)threadIdx.x;

    // Wave-uniform row data: scalar loads, every thread redundantly computes
    // the 3x3 inverse (cheap, removes a barrier + LDS round-trip).
    const int bi = batch[i];
    const float pix = pos[i * 3 + 0];
    const float piy = pos[i * 3 + 1];
    const float piz = pos[i * 3 + 2];

    const float* C = cell + bi * 9;
    const float C00 = C[0], C01 = C[1], C02 = C[2];
    const float C10 = C[3], C11 = C[4], C12 = C[5];
    const float C20 = C[6], C21 = C[7], C22 = C[8];
    // A = inv(C^T) = cofactor(C) / det(C)
    const float cof00 =  (C11 * C22 - C12 * C21);
    const float cof01 = -(C10 * C22 - C12 * C20);
    const float cof02 =  (C10 * C21 - C11 * C20);
    const float cof10 = -(C01 * C22 - C02 * C21);
    const float cof11 =  (C00 * C22 - C02 * C20);
    const float cof12 = -(C00 * C21 - C01 * C20);
    const float cof20 =  (C01 * C12 - C02 * C11);
    const float cof21 = -(C00 * C12 - C02 * C10);
    const float cof22 =  (C00 * C11 - C01 * C10);
    const float det = C00 * cof00 + C01 * cof01 + C02 * cof02;
    const float id  = 1.0f / det;
    const float A00 = cof00 * id, A01 = cof01 * id, A02 = cof02 * id;
    const float A10 = cof10 * id, A11 = cof11 * id, A12 = cof12 * id;
    const float A20 = cof20 * id, A21 = cof21 * id, A22 = cof22 * id;

    const int j0 = jc * JPB + tid * JPT;

    // 12 contiguous floats: pos[j0..j0+3][0..2]  (j0*3 is a multiple of 4)
    const float4* pj = (const float4*)(pos + (size_t)j0 * 3);
    const float4 q0 = pj[0], q1 = pj[1], q2 = pj[2];
    const int4 bj4 = *(const int4*)(batch + j0);

    const float pjx[4] = { q0.x, q0.w, q1.z, q2.y };
    const float pjy[4] = { q0.y, q1.x, q1.w, q2.z };
    const float pjz[4] = { q0.z, q1.y, q2.x, q2.w };
    const int   bj[4]  = { bj4.x, bj4.y, bj4.z, bj4.w };

    float od[12];
    float om[4];

    #pragma unroll
    for (int t = 0; t < 4; ++t) {
        const int j = j0 + t;
        // raw displacement, exact-order f32 (matches numpy, no fma contraction)
        const float d0 = __fsub_rn(pix, pjx[t]);
        const float d1 = __fsub_rn(piy, pjy[t]);
        const float d2 = __fsub_rn(piz, pjz[t]);

        // scaled = inv(cell^T) @ d   (ulp noise here is harmless: it only
        // matters near scaled==±0.5, i.e. half-cell disp >> R, masked out)
        const float s0 = __fadd_rn(__fadd_rn(__fmul_rn(A00, d0), __fmul_rn(A01, d1)), __fmul_rn(A02, d2));
        const float s1 = __fadd_rn(__fadd_rn(__fmul_rn(A10, d0), __fmul_rn(A11, d1)), __fmul_rn(A12, d2));
        const float s2 = __fadd_rn(__fadd_rn(__fmul_rn(A20, d0), __fmul_rn(A21, d1)), __fmul_rn(A22, d2));

        const float r0 = rintf(s0);   // round-half-even == jnp.round
        const float r1 = rintf(s1);
        const float r2 = rintf(s2);

        // wrapped = d - cell @ r, exact numpy order, no contraction
        const float w0 = __fsub_rn(d0, __fadd_rn(__fadd_rn(__fmul_rn(C00, r0), __fmul_rn(C01, r1)), __fmul_rn(C02, r2)));
        const float w1 = __fsub_rn(d1, __fadd_rn(__fadd_rn(__fmul_rn(C10, r0), __fmul_rn(C11, r1)), __fmul_rn(C12, r2)));
        const float w2 = __fsub_rn(d2, __fadd_rn(__fadd_rn(__fmul_rn(C20, r0), __fmul_rn(C21, r1)), __fmul_rn(C22, r2)));

        const float n2 = __fadd_rn(__fadd_rn(__fmul_rn(w0, w0), __fmul_rn(w1, w1)), __fmul_rn(w2, w2));
        const bool m = (bi == bj[t]) && (i != j) && (sqrtf(n2) < R_CUT);

        od[t * 3 + 0] = m ? w0 : 0.0f;
        od[t * 3 + 1] = m ? w1 : 0.0f;
        od[t * 3 + 2] = m ? w2 : 0.0f;
        om[t] = m ? 1.0f : 0.0f;
    }

    // --- Stage disp through LDS so global stores are lane-contiguous ---
    // Write: thread tid -> float4 slots [3*tid, 3*tid+2]; start bank
    // (12*tid+4s) mod 32 — each 8 consecutive lanes tile all 32 banks once:
    // conflict-free. Read: lane-linear b128, conflict-free.
    float4* lb = (float4*)sBuf;
    lb[tid * 3 + 0] = make_float4(od[0], od[1], od[2],  od[3]);
    lb[tid * 3 + 1] = make_float4(od[4], od[5], od[6],  od[7]);
    lb[tid * 3 + 2] = make_float4(od[8], od[9], od[10], od[11]);

    // mask store: already coalesced (16 B/lane, lane-contiguous)
    float4* mout = (float4*)(mask_out + (size_t)i * NATOMS + (size_t)jc * JPB);
    mout[tid] = make_float4(om[0], om[1], om[2], om[3]);

    __syncthreads();

    // Coalesced disp stores: 768 float4 per block, 3 per thread,
    // instruction s covers float4 range [s*256, s*256+255] — 4 KB/wave/instr.
    float4* gb = (float4*)(disp_out + (size_t)i * (NATOMS * 3) + (size_t)jc * (JPB * 3));
    gb[0 * BLOCK + tid] = lb[0 * BLOCK + tid];
    gb[1 * BLOCK + tid] = lb[1 * BLOCK + tid];
    gb[2 * BLOCK + tid] = lb[2 * BLOCK + tid];
}

extern "C" void kernel_launch(void* const* d_in, const int* in_sizes, int n_in,
                              void* d_out, int out_size, void* d_ws, size_t ws_size,
                              hipStream_t stream) {
    const float* pos   = (const float*)d_in[0];
    const float* cell  = (const float*)d_in[1];
    const int*   batch = (const int*)d_in[2];

    float* disp_out = (float*)d_out;
    float* mask_out = (float*)d_out + (size_t)NATOMS * NATOMS * 3;

    const int blocks = NATOMS * (NATOMS / JPB);  // 4096 * 4 = 16384
    radius_graph_kernel<<<blocks, BLOCK, 0, stream>>>(pos, cell, batch, disp_out, mask_out);
}